// Round 1
// baseline (194.969 us; speedup 1.0000x reference)
//
#include <hip/hip_runtime.h>
#include <math.h>

// Problem shape (fixed by setup_inputs): x (32,1024,1024) f32, weight (1024,1024) f32,
// bias (1024,) f32, out (32,1,1024) f32.
//
// Semantics: fix_x(x) = clamp(floor(32x)/32, -127/32, 127/32). All post-fix values are
// k/32 with k in [-127,127] -> exact integer domain. The scan is a saturating integer
// fold, parallelized via the clamped-shift-function monoid:
//   f(a)=clamp(a+s,L,U);  (G∘F) = (sF+sG, clamp(LF+sG,LG,UG), clamp(UF+sG,LG,UG))
// init (elem 1023) folds in as constant fn (0,v,v) so the total has L==U==acc.
// Element 0's function is OUTERMOST (scan processes 1022..0 after init=1023).
//
// R5: one wave per (b,o) row. Previous structure (4 waves/row, 4 elems/lane) paid a
// full 6-step butterfly (18 ds_bpermute + ~78 VALU) + LDS exchange + barrier per
// FOUR serial elements -> DS pipe ~19us + VALU ~15us vs 21us HBM floor. Now each
// lane serially composes 16 contiguous elements (~9 VALU/elem, exact fp32 integer
// arithmetic, no cvt), then ONE butterfly, zero LDS, zero __syncthreads. 4x fewer
// waves, ~5x fewer DS ops, ~2x fewer VALU cycles, same bytes/VMEM instr count
// (4x dwordx4 per stream; the 4 back-to-back loads cover the full 4KB row, L1
// merges them). XCD swizzle kept: 8 same-o blocks land on one XCD, the block's
// 4 waves (4 b-values) share the w row in L1.

#define IN_DIM  1024
#define OUT_DIM 1024
#define B_DIM   32

typedef float vfloat4 __attribute__((ext_vector_type(4)));

__global__ __launch_bounds__(256) void ffl_kernel(
    const float* __restrict__ x,
    const float* __restrict__ w,
    const float* __restrict__ bias,
    float* __restrict__ out)
{
    const int lane = threadIdx.x & 63;
    const int wid  = threadIdx.x >> 6;   // wave = row within block

    // 8192 blocks. xcd = blk&7 owns o-band [xcd*128, xcd*128+128); the 8 blocks
    // covering one o (8 b-groups) are 8 apart in blockIdx -> same XCD.
    const int xcd = blockIdx.x & 7;
    const int j   = blockIdx.x >> 3;          // 0..1023
    const int o   = (xcd << 7) | (j >> 3);    // 128 o-rows per XCD band
    const int b   = ((j & 7) << 2) | wid;     // 8 b-groups x 4 waves = 32 b

    const size_t rowx = ((size_t)b * OUT_DIM + o) * (size_t)IN_DIM;
    const size_t roww = (size_t)o * IN_DIM;
    const int    base = lane << 4;            // 16 contiguous elems per lane

    // 4x dwordx4 per stream; lane stride 64B, the 4 loads tile the full 4KB row.
    vfloat4 xv[4], wv[4];
    #pragma unroll
    for (int c = 0; c < 4; ++c)
        xv[c] = *(const vfloat4*)(x + rowx + base + (c << 2));
    #pragma unroll
    for (int c = 0; c < 4; ++c)
        wv[c] = *(const vfloat4*)(w + roww + base + (c << 2));

    // Running composed function over this lane's 16 contiguous elems, fp32 integer
    // domain (all values small ints, exact; min(max()) -> v_med3_f32).
    // Running is OUTER (lower element index applied later in the scan).
    float rs = 0.0f;
    float rL = -268435456.0f;   // -2^28: identity bounds
    float rU =  268435456.0f;

    #pragma unroll
    for (int c = 0; c < 4; ++c) {
        float px[4] = { xv[c].x * wv[c].x, xv[c].y * wv[c].y,
                        xv[c].z * wv[c].z, xv[c].w * wv[c].w };
        #pragma unroll
        for (int k = 0; k < 4; ++k) {
            // quantize: v = clamp(floor(32*(x*w)), -127, 127); (x*w) rounds first
            // (matches JAX), *32 exact (pow2).
            float t = floorf(px[k] * 32.0f);
            t = fminf(fmaxf(t, -127.0f), 127.0f);
            // element 1023 (lane 63, last elem) is the scan init -> constant fn (0,v,v)
            const bool isInit = (c == 3) && (k == 3) && (lane == 63);
            float sE = isInit ? 0.0f : t;
            float LE = isInit ? t : -127.0f;
            float UE = isInit ? t : 127.0f;
            // new = running ∘ elem (elem inner): push elem bounds through running
            float nL = fminf(fmaxf(LE + rs, rL), rU);
            float nU = fminf(fmaxf(UE + rs, rL), rU);
            rs += sE; rL = nL; rU = nU;
        }
    }

    // 6-step butterfly: lane with lower index (lower elements) is the OUTER function.
    // s-combine is commutative (plain add); only bounds need direction selects.
    #pragma unroll
    for (int m = 1; m < 64; m <<= 1) {
        float ps = __shfl_xor(rs, m, 64);
        float pL = __shfl_xor(rL, m, 64);
        float pU = __shfl_xor(rU, m, 64);
        const bool lower = ((lane & m) == 0);
        float sG = lower ? rs : ps;   // outer shift
        float LG = lower ? rL : pL;
        float UG = lower ? rU : pU;
        float LF = lower ? pL : rL;   // inner bounds
        float UF = lower ? pU : rU;
        rs = rs + ps;
        rL = fminf(fmaxf(LF + sG, LG), UG);
        rU = fminf(fmaxf(UF + sG, LG), UG);
    }

    if (lane == 0) {
        // rL == rU == acc (init constant-fn collapses the interval). Exact int in fp32.
        float acc = rL * 0.03125f;          // /32 exact (pow2)
        float tb  = acc + bias[o];          // single fp32 rounding, matches ref
        float r   = floorf(tb * 32.0f);     // *32 exact
        r = fminf(fmaxf(r, -127.0f), 127.0f);
        out[(size_t)b * OUT_DIM + o] = r * 0.03125f;
    }
}

extern "C" void kernel_launch(void* const* d_in, const int* in_sizes, int n_in,
                              void* d_out, int out_size, void* d_ws, size_t ws_size,
                              hipStream_t stream) {
    const float* x    = (const float*)d_in[0];
    const float* w    = (const float*)d_in[1];
    const float* bias = (const float*)d_in[2];
    float* out = (float*)d_out;

    const int blocks = (B_DIM * OUT_DIM) / 4;   // 8192 blocks, 4 rows (waves) each
    ffl_kernel<<<blocks, 256, 0, stream>>>(x, w, bias, out);
}